// Round 1
// baseline (1173.985 us; speedup 1.0000x reference)
//
#include <hip/hip_runtime.h>
#include <math.h>

// ---------------------------------------------------------------------------
// OctreeAttention fused: K0 weight prep -> K1 (qkv GEMM + RoPE + attention)
//                        -> K2 (proj GEMM).
// N=400000 divisible by 128 -> no padding anywhere.
// d_out doubles as scratch: K1 writes bf16 attn-out into the FIRST 64KB of
// each block's own 128KB output region; K2 reads it (fully, into LDS, before
// the barrier) then overwrites the region with f32 output. No cross-block
// overlap -> race-free and graph-replay deterministic.
// ---------------------------------------------------------------------------

typedef float  float4v __attribute__((ext_vector_type(4)));
typedef short  bf16x8  __attribute__((ext_vector_type(8)));   // 8 bf16 = 4 VGPR
typedef unsigned short us4 __attribute__((ext_vector_type(4)));

#define SCALE_ 0.17677669529663687f   // 32^-0.5

__device__ __forceinline__ unsigned short f2bf(float x) {
  union { float f; unsigned u; } v; v.f = x;
  unsigned r = v.u + 0x7FFFu + ((v.u >> 16) & 1u);   // RNE
  return (unsigned short)(r >> 16);
}

__device__ __forceinline__ float4v mfma16(bf16x8 a, bf16x8 b, float4v c) {
  return __builtin_amdgcn_mfma_f32_16x16x32_bf16(a, b, c, 0, 0, 0);
}

// ------------------------------- K0: weights -------------------------------
// wqkv_t[co][ci] = bf16(Wqkv[ci][co])   (768 x 256)
// wproj_t[co][ci] = bf16(Wproj[ci][co]) (256 x 256)
__global__ __launch_bounds__(256) void k_prep(const float* __restrict__ wqkv,
                                              const float* __restrict__ wproj,
                                              unsigned short* __restrict__ wq,
                                              unsigned short* __restrict__ wp) {
  int tid = blockIdx.x * 256 + threadIdx.x;
  if (tid < 768 * 256) {
    int co = tid >> 8, ci = tid & 255;
    wq[tid] = f2bf(wqkv[ci * 768 + co]);
  } else {
    int u = tid - 768 * 256;
    int co = u >> 8, ci = u & 255;
    wp[u] = f2bf(wproj[ci * 256 + co]);
  }
}

// ------------------------------- K1: fused ---------------------------------
// LDS map (unsigned short units):
//   A_s  [128][264]        @ 0       (67584 B)  data tile bf16, padded stride
//   QK_s [4][128][40]      @ 33792   (40960 B)  mats: q_h0,q_h1,k_h0,k_h1 (prow-major)
//   VT_s [2][32][136]      @ 54272   (17408 B)  V transposed: [f][prow]
//   PL_s [8][32][40]       @ 62976   (20480 B)  per-wave P tile (C-layout -> A-layout fix)
//   ML_s int[128]          @ 73216us (512 B)    depths in prow order
#define K1_LDS_BYTES 146944

__global__ __launch_bounds__(512) void k_fused(
    const float* __restrict__ data, const float* __restrict__ xyz,
    const int* __restrict__ depth, const float* __restrict__ bqkv,
    const float* __restrict__ freqs, const unsigned short* __restrict__ wqkv_t,
    unsigned short* __restrict__ aout /* d_out viewed as bf16 */) {
  extern __shared__ unsigned short smem[];
  unsigned short* A_s  = smem;
  unsigned short* QK_s = smem + 33792;
  unsigned short* VT_s = smem + 54272;
  unsigned short* PL_s = smem + 62976;
  int* ML_s = (int*)(smem + 73216);

  const int b   = blockIdx.x;
  const int t   = threadIdx.x;
  const int lane = t & 63;
  const int w   = t >> 6;          // wave 0..7
  const int wm  = w >> 1;          // row quarter (32 rows)
  const int wn  = w & 1;           // col half (96 of 192)
  const int g   = lane >> 4;       // 0..3
  const int l15 = lane & 15;

  // stage data[b*128..+128][0..256) as bf16 into A_s [128][264]
  {
    const float* src = data + (size_t)b * (128 * 256);
#pragma unroll
    for (int i = 0; i < 16; ++i) {
      int idx = t + i * 512;               // quad id 0..8191
      int row = idx >> 6;
      int c4  = (idx & 63) << 2;
      const float4v v4 = *reinterpret_cast<const float4v*>(src + row * 256 + c4);
      us4 pk;
      pk.x = f2bf(v4.x); pk.y = f2bf(v4.y); pk.z = f2bf(v4.z); pk.w = f2bf(v4.w);
      *reinterpret_cast<us4*>(A_s + row * 264 + c4) = pk;
    }
  }
  // depths in prow order: prow = d*32 + kk  <->  n_local = kk*4 + d
  if (t < 128) {
    ML_s[t] = depth[b * 128 + ((t & 31) << 2) + (t >> 5)];
  }
  // hoist xyz for this thread's 8 GEMM-output rows
  float xr[8][3];
#pragma unroll
  for (int q8 = 0; q8 < 8; ++q8) {
    int mt = q8 >> 2, rr = q8 & 3;
    int row = wm * 32 + mt * 16 + 4 * g + rr;
    const float* xp = xyz + (size_t)(b * 128 + row) * 3;
    xr[q8][0] = xp[0]; xr[q8][1] = xp[1]; xr[q8][2] = xp[2];
  }
  __syncthreads();

  const int d_grp = wm;   // attention group for this wave
  const int hh    = wn;   // head parity within the pair

  for (int hp = 0; hp < 4; ++hp) {
    // ---- GEMM: cols = {q,k,v} strips for heads (2hp, 2hp+1); this wave: 32 rows x 96 cols
    float4v acc[2][6];
#pragma unroll
    for (int mt = 0; mt < 2; ++mt)
#pragma unroll
      for (int nt = 0; nt < 6; ++nt) acc[mt][nt] = (float4v){0.f, 0.f, 0.f, 0.f};

    int browg[6];   // wqkv_t row (= qkv output column) per n-tile
#pragma unroll
    for (int nt = 0; nt < 6; ++nt) {
      int nl = wn * 96 + nt * 16;
      browg[nt] = (nl >> 6) * 256 + hp * 64 + (nl & 63) + l15;
    }
#pragma unroll
    for (int k0 = 0; k0 < 256; k0 += 32) {
      const int kcol = k0 + 8 * g;
      bf16x8 af0 = *reinterpret_cast<const bf16x8*>(A_s + (wm * 32 + l15) * 264 + kcol);
      bf16x8 af1 = *reinterpret_cast<const bf16x8*>(A_s + (wm * 32 + 16 + l15) * 264 + kcol);
#pragma unroll
      for (int nt = 0; nt < 6; ++nt) {
        bf16x8 bf_ = *reinterpret_cast<const bf16x8*>(wqkv_t + (size_t)browg[nt] * 256 + kcol);
        acc[0][nt] = mfma16(af0, bf_, acc[0][nt]);
        acc[1][nt] = mfma16(af1, bf_, acc[1][nt]);
      }
    }

    // ---- epilogue: bias + RoPE (q,k) -> QK_s ; v -> VT_s (transposed)
#pragma unroll
    for (int np = 0; np < 3; ++np) {
      const int nt0 = np * 2, nt1 = nt0 + 1;
      const int nl0 = wn * 96 + nt0 * 16;      // multiple of 32
      const int strip = nl0 >> 6;              // 0=q 1=k 2=v
      const int hloc = (nl0 >> 5) & 1;         // head within pair
      const int cm0 = hp * 64 + (nl0 & 63) + l15;   // col within matrix, f = l15 in [0,16)
      const float b0 = bqkv[strip * 256 + cm0];
      const float b1 = bqkv[strip * 256 + cm0 + 16];
      float F0 = 0.f, F1 = 0.f, F2 = 0.f;
      if (strip < 2) {
        const float* fp = freqs + ((hp * 2 + hloc) * 16 + l15) * 3;
        F0 = fp[0]; F1 = fp[1]; F2 = fp[2];
      }
#pragma unroll
      for (int q8 = 0; q8 < 8; ++q8) {
        const int mt = q8 >> 2, rr = q8 & 3;
        const int row = wm * 32 + mt * 16 + 4 * g + rr;
        const int prow = ((row & 3) << 5) | (row >> 2);
        float v0 = acc[mt][nt0][rr] + b0;
        float v1 = acc[mt][nt1][rr] + b1;
        if (strip < 2) {
          float th = xr[q8][0] * F0 + xr[q8][1] * F1 + xr[q8][2] * F2;
          float sn, cs;
          __sincosf(th, &sn, &cs);
          float o0 = v0 * cs - v1 * sn;   // f < 16 : x*cos - x[f+16]*sin
          float o1 = v1 * cs + v0 * sn;   // f >= 16: x*cos + x[f-16]*sin
          unsigned short* dst = QK_s + (strip * 2 + hloc) * 5120 + prow * 40;
          dst[l15]      = f2bf(o0);
          dst[l15 + 16] = f2bf(o1);
        } else {
          unsigned short* dst = VT_s + hloc * 4352;
          dst[l15 * 136 + prow]        = f2bf(v0);
          dst[(l15 + 16) * 136 + prow] = f2bf(v1);
        }
      }
    }
    __syncthreads();

    // ---- attention: this wave handles (group d_grp, head h = 2hp + hh)
    {
      const unsigned short* qm = QK_s + hh * 5120;
      const unsigned short* km = QK_s + (2 + hh) * 5120;
      bf16x8 aq0 = *reinterpret_cast<const bf16x8*>(qm + (d_grp * 32 + l15) * 40 + 8 * g);
      bf16x8 aq1 = *reinterpret_cast<const bf16x8*>(qm + (d_grp * 32 + 16 + l15) * 40 + 8 * g);
      bf16x8 bk0 = *reinterpret_cast<const bf16x8*>(km + (d_grp * 32 + l15) * 40 + 8 * g);
      bf16x8 bk1 = *reinterpret_cast<const bf16x8*>(km + (d_grp * 32 + 16 + l15) * 40 + 8 * g);
      float4v s00 = (float4v){0.f,0.f,0.f,0.f}, s01 = s00, s10 = s00, s11 = s00;
      s00 = mfma16(aq0, bk0, s00);
      s01 = mfma16(aq0, bk1, s01);
      s10 = mfma16(aq1, bk0, s10);
      s11 = mfma16(aq1, bk1, s11);

      const int mk0 = ML_s[d_grp * 32 + l15];
      const int mk1 = ML_s[d_grp * 32 + 16 + l15];
      unsigned short* plw = PL_s + w * 1280;
      float rs[8];
#pragma unroll
      for (int q8 = 0; q8 < 8; ++q8) {
        const int mt = q8 >> 2, rr = q8 & 3;
        const int q_idx = mt * 16 + 4 * g + rr;
        const int mq = ML_s[d_grp * 32 + q_idx];
        float sv0 = (mt ? s10[rr] : s00[rr]) * SCALE_ + (mq < mk0 ? -1000.f : 0.f);
        float sv1 = (mt ? s11[rr] : s01[rr]) * SCALE_ + (mq < mk1 ? -1000.f : 0.f);
        float mx = fmaxf(sv0, sv1);
        mx = fmaxf(mx, __shfl_xor(mx, 1));
        mx = fmaxf(mx, __shfl_xor(mx, 2));
        mx = fmaxf(mx, __shfl_xor(mx, 4));
        mx = fmaxf(mx, __shfl_xor(mx, 8));
        float p0 = __expf(sv0 - mx);
        float p1 = __expf(sv1 - mx);
        float sm = p0 + p1;
        sm += __shfl_xor(sm, 1);
        sm += __shfl_xor(sm, 2);
        sm += __shfl_xor(sm, 4);
        sm += __shfl_xor(sm, 8);
        rs[q8] = 1.0f / sm;
        plw[q_idx * 40 + l15]      = f2bf(p0);   // un-normalized P
        plw[q_idx * 40 + 16 + l15] = f2bf(p1);
      }
      // P (wave-private LDS) -> A-fragments; V^T -> B-fragments
      bf16x8 ap0 = *reinterpret_cast<const bf16x8*>(plw + l15 * 40 + 8 * g);
      bf16x8 ap1 = *reinterpret_cast<const bf16x8*>(plw + (16 + l15) * 40 + 8 * g);
      const unsigned short* vt = VT_s + hh * 4352;
      bf16x8 bv0 = *reinterpret_cast<const bf16x8*>(vt + l15 * 136 + d_grp * 32 + 8 * g);
      bf16x8 bv1 = *reinterpret_cast<const bf16x8*>(vt + (16 + l15) * 136 + d_grp * 32 + 8 * g);
      float4v o00 = (float4v){0.f,0.f,0.f,0.f}, o01 = o00, o10 = o00, o11 = o00;
      o00 = mfma16(ap0, bv0, o00);
      o01 = mfma16(ap0, bv1, o01);
      o10 = mfma16(ap1, bv0, o10);
      o11 = mfma16(ap1, bv1, o11);

      const int h = hp * 2 + hh;
      unsigned short* ob = aout + (size_t)b * 65536 + h * 32;
#pragma unroll
      for (int q8 = 0; q8 < 8; ++q8) {
        const int mt = q8 >> 2, rr = q8 & 3;
        const int q_idx = mt * 16 + 4 * g + rr;
        const float r = rs[q8];
        float e0 = (mt ? o10[rr] : o00[rr]) * r;
        float e1 = (mt ? o11[rr] : o01[rr]) * r;
        unsigned short* op = ob + (size_t)(q_idx * 4 + d_grp) * 256;  // back to point order
        op[l15]      = f2bf(e0);
        op[16 + l15] = f2bf(e1);
      }
    }
    __syncthreads();
  }
}

// ------------------------------- K2: proj ----------------------------------
#define K2_LDS_BYTES 67584

__global__ __launch_bounds__(512) void k_proj(
    const unsigned short* ain,                       // d_out bf16 (aliases out!)
    const unsigned short* __restrict__ wproj_t,
    const float* __restrict__ bproj,
    float* out) {
  extern __shared__ unsigned short smem2[];
  unsigned short* A_s = smem2;                       // [128][264]
  const int b = blockIdx.x, t = threadIdx.x;
  const int lane = t & 63, w = t >> 6;
  const int wm = w >> 1, wn = w & 1;
  const int g = lane >> 4, l15 = lane & 15;

  {  // stage this block's attn-out (all global reads of the region happen here)
    const unsigned short* src = ain + (size_t)b * 65536;
#pragma unroll
    for (int i = 0; i < 8; ++i) {
      int c = t + i * 512;
      int row = c >> 5, c8 = (c & 31) << 3;
      *reinterpret_cast<bf16x8*>(A_s + row * 264 + c8) =
          *reinterpret_cast<const bf16x8*>(src + row * 256 + c8);
    }
  }
  __syncthreads();

  float4v acc[2][8];
#pragma unroll
  for (int mt = 0; mt < 2; ++mt)
#pragma unroll
    for (int nt = 0; nt < 8; ++nt) acc[mt][nt] = (float4v){0.f, 0.f, 0.f, 0.f};

#pragma unroll
  for (int k0 = 0; k0 < 256; k0 += 32) {
    const int kcol = k0 + 8 * g;
    bf16x8 af0 = *reinterpret_cast<const bf16x8*>(A_s + (wm * 32 + l15) * 264 + kcol);
    bf16x8 af1 = *reinterpret_cast<const bf16x8*>(A_s + (wm * 32 + 16 + l15) * 264 + kcol);
#pragma unroll
    for (int nt = 0; nt < 8; ++nt) {
      const int col = wn * 128 + nt * 16 + l15;
      bf16x8 bf_ = *reinterpret_cast<const bf16x8*>(wproj_t + (size_t)col * 256 + kcol);
      acc[0][nt] = mfma16(af0, bf_, acc[0][nt]);
      acc[1][nt] = mfma16(af1, bf_, acc[1][nt]);
    }
  }
#pragma unroll
  for (int nt = 0; nt < 8; ++nt) {
    const int col = wn * 128 + nt * 16 + l15;
    const float bb = bproj[col];
#pragma unroll
    for (int q8 = 0; q8 < 8; ++q8) {
      const int mt = q8 >> 2, rr = q8 & 3;
      const int row = wm * 32 + mt * 16 + 4 * g + rr;
      out[((size_t)b * 128 + row) * 256 + col] = acc[mt][nt][rr] + bb;
    }
  }
}

// ----------------------------- launch --------------------------------------
extern "C" void kernel_launch(void* const* d_in, const int* in_sizes, int n_in,
                              void* d_out, int out_size, void* d_ws, size_t ws_size,
                              hipStream_t stream) {
  const float* data  = (const float*)d_in[0];
  const float* xyz   = (const float*)d_in[1];
  const int*   depth = (const int*)d_in[2];
  const float* wqkv  = (const float*)d_in[3];
  const float* bqkv  = (const float*)d_in[4];
  const float* wproj = (const float*)d_in[5];
  const float* bproj = (const float*)d_in[6];
  const float* freqs = (const float*)d_in[7];

  unsigned short* wqkv_t  = (unsigned short*)d_ws;          // [768][256] bf16
  unsigned short* wproj_t = wqkv_t + 768 * 256;             // [256][256] bf16

  (void)hipFuncSetAttribute(reinterpret_cast<const void*>(k_fused),
                            hipFuncAttributeMaxDynamicSharedMemorySize, K1_LDS_BYTES);
  (void)hipFuncSetAttribute(reinterpret_cast<const void*>(k_proj),
                            hipFuncAttributeMaxDynamicSharedMemorySize, K2_LDS_BYTES);

  k_prep<<<dim3(1024), dim3(256), 0, stream>>>(wqkv, wproj, wqkv_t, wproj_t);
  k_fused<<<dim3(3125), dim3(512), K1_LDS_BYTES, stream>>>(
      data, xyz, depth, bqkv, freqs, wqkv_t, (unsigned short*)d_out);
  k_proj<<<dim3(3125), dim3(512), K2_LDS_BYTES, stream>>>(
      (const unsigned short*)d_out, wproj_t, bproj, (float*)d_out);
}